// Round 1
// baseline (1577.898 us; speedup 1.0000x reference)
//
#include <hip/hip_runtime.h>

// Problem constants: B=32, S=512, I=128, H=128, O=32, 3H=384
// out = [ y (32*32) | jcbT (512*32*128*128) ]  fp32
//
// ws layout (floats):
//   ih    : 0            .. 6291456      (S*B*384)
//   coef  : 6291456      .. +8388608     (S*B*128 float4: cr,cn,cz,z)
//   wt    : 14680064     .. +49152       (W_hh^T as [3][128][128], wt[g][i][j]=W_hh[g*128+j][i])
//   hlast : 14729216     .. +4096

// ---------------- K0: transpose W_hh ----------------
__global__ void k0_transpose(const float* __restrict__ whh, float* __restrict__ wt) {
    int idx = blockIdx.x * 256 + threadIdx.x;          // 49152 total
    int g3 = idx >> 14;
    int r  = idx & 16383;
    int i  = r >> 7, j = r & 127;
    wt[idx] = whh[(g3 * 128 + j) * 128 + i];
}

// ---------------- K1: ih = xs @ W_ih^T + b_ih ----------------
// M=16384 (m = s*32+b), N=384 (g), K=128. 64x64 tile, 4x4 per thread.
__global__ __launch_bounds__(256) void k1_gemm_ih(const float* __restrict__ x,
                                                  const float* __restrict__ wih,
                                                  const float* __restrict__ bih,
                                                  float* __restrict__ ih) {
    __shared__ float a_lds[64 * 129];
    __shared__ float b_lds[64 * 129];
    int t  = threadIdx.x;
    int m0 = blockIdx.x * 64;
    int g0 = blockIdx.y * 64;

    int row = t >> 2;            // 64 rows
    int kq  = (t & 3) * 32;      // 4 k-quarters
    {
        int m = m0 + row;
        int b = m & 31, s = m >> 5;
        const float* xr = x + b * (512 * 128) + s * 128;
        const float* wr = wih + (g0 + row) * 128;
        #pragma unroll
        for (int u = 0; u < 8; u++) {
            int k = kq + u * 4;
            float4 va = *(const float4*)(xr + k);
            float4 vb = *(const float4*)(wr + k);
            a_lds[row * 129 + k + 0] = va.x; a_lds[row * 129 + k + 1] = va.y;
            a_lds[row * 129 + k + 2] = va.z; a_lds[row * 129 + k + 3] = va.w;
            b_lds[row * 129 + k + 0] = vb.x; b_lds[row * 129 + k + 1] = vb.y;
            b_lds[row * 129 + k + 2] = vb.z; b_lds[row * 129 + k + 3] = vb.w;
        }
    }
    __syncthreads();

    int mi = (t & 15) * 4;
    int gi = (t >> 4) * 4;
    float acc[4][4] = {};
    #pragma unroll 4
    for (int k = 0; k < 128; k++) {
        float av[4], bv[4];
        #pragma unroll
        for (int ii = 0; ii < 4; ii++) av[ii] = a_lds[(mi + ii) * 129 + k];
        #pragma unroll
        for (int jj = 0; jj < 4; jj++) bv[jj] = b_lds[(gi + jj) * 129 + k];
        #pragma unroll
        for (int ii = 0; ii < 4; ii++)
            #pragma unroll
            for (int jj = 0; jj < 4; jj++)
                acc[ii][jj] += av[ii] * bv[jj];
    }
    float4 bias = *(const float4*)(bih + g0 + gi);
    #pragma unroll
    for (int ii = 0; ii < 4; ii++) {
        float4 v = make_float4(acc[ii][0] + bias.x, acc[ii][1] + bias.y,
                               acc[ii][2] + bias.z, acc[ii][3] + bias.w);
        *(float4*)(ih + (m0 + mi + ii) * 384 + g0 + gi) = v;
    }
}

// ---------------- K2: sequential scan, one block per batch row ----------------
// 384 threads: thread g owns gate-output g. W_hh row g in 128 VGPRs.
__global__ __launch_bounds__(384) void k2_scan(const float* __restrict__ ih,
                                               const float* __restrict__ whh,
                                               const float* __restrict__ bhh,
                                               float4* __restrict__ coef,
                                               float* __restrict__ hlast) {
    int b = blockIdx.x;
    int g = threadIdx.x;
    __shared__ __align__(16) float h[128];
    __shared__ float rz[256];

    float4 w[32];
    const float4* wrow = (const float4*)(whh + g * 128);
    #pragma unroll
    for (int kk = 0; kk < 32; kk++) w[kk] = wrow[kk];
    float bh = bhh[g];
    if (g < 128) h[g] = 0.f;
    __syncthreads();

    for (int s = 0; s < 512; s++) {
        float ihv = ih[(s * 32 + b) * 384 + g];   // issued early, coalesced
        float a0 = 0.f, a1 = 0.f, a2 = 0.f, a3 = 0.f;
        #pragma unroll
        for (int kk = 0; kk < 32; kk++) {
            float4 hv = ((const float4*)h)[kk];   // wave-uniform broadcast
            a0 += w[kk].x * hv.x;
            a1 += w[kk].y * hv.y;
            a2 += w[kk].z * hv.z;
            a3 += w[kk].w * hv.w;
        }
        float hh = bh + ((a0 + a1) + (a2 + a3));
        if (g < 256) {
            float p = ihv + hh;
            rz[g] = 1.f / (1.f + __expf(-p));
        }
        __syncthreads();
        if (g >= 256) {
            int j = g - 256;
            float r  = rz[j];
            float z  = rz[128 + j];
            float M  = hh;                        // includes b_hh, matches ref
            float hp = h[j];
            float e  = __expf(2.f * (ihv + r * M));
            float n  = 1.f - 2.f / (e + 1.f);     // tanh
            float c67 = (1.f - n * n) * (1.f - z);
            coef[(s * 32 + b) * 128 + j] =
                make_float4(r * (1.f - r) * M * c67,   // cr  -> Wr^T
                            r * c67,                   // cn  -> Wn^T
                            z * (1.f - z) * (hp - n),  // cz  -> Wz^T
                            z);                        // diag
            h[j] = (1.f - z) * n + z * hp;
        }
        __syncthreads();
    }
    if (g >= 256) hlast[b * 128 + (g - 256)] = h[g - 256];
}

// ---------------- K3: Jacobian materialization (the 1 GiB write) ----------------
// grid (256 sb-chunks of 64, 4 i-tiles of 32). W^T tiles in LDS (48 KB).
__global__ __launch_bounds__(256) void k3_jac(const float4* __restrict__ coef,
                                              const float* __restrict__ wt,
                                              float* __restrict__ out) {
    __shared__ float wlds[3 * 32 * 128];
    int t  = threadIdx.x;
    int i0 = blockIdx.y * 32;
    #pragma unroll
    for (int g3 = 0; g3 < 3; g3++) {
        const float4* src = (const float4*)(wt + g3 * 16384 + i0 * 128);
        float4* dst = (float4*)(wlds + g3 * 4096);
        #pragma unroll
        for (int r = 0; r < 4; r++) dst[r * 256 + t] = src[r * 256 + t];
    }
    __syncthreads();

    int il = t >> 5;             // 8 i-rows per pass
    int j4 = (t & 31) * 4;       // 128 j per 32 lanes (float4)
    int m0 = blockIdx.x * 64;

    for (int c = 0; c < 64; c++) {
        int m = m0 + c;
        int s = m >> 5, b = m & 31;
        float4 q0 = coef[m * 128 + j4 + 0];
        float4 q1 = coef[m * 128 + j4 + 1];
        float4 q2 = coef[m * 128 + j4 + 2];
        float4 q3 = coef[m * 128 + j4 + 3];
        float* ob = out + 1024 + (((511 - s) * 32 + b) << 14);   // flip(s)
        #pragma unroll
        for (int ii = 0; ii < 4; ii++) {
            int iloc = il + ii * 8;
            int i = i0 + iloc;
            float4 wr = *(const float4*)(wlds + 0 * 4096 + iloc * 128 + j4);
            float4 wz = *(const float4*)(wlds + 1 * 4096 + iloc * 128 + j4);
            float4 wn = *(const float4*)(wlds + 2 * 4096 + iloc * 128 + j4);
            float4 v;
            v.x = wr.x * q0.x + wn.x * q0.y + wz.x * q0.z + ((i == j4 + 0) ? q0.w : 0.f);
            v.y = wr.y * q1.x + wn.y * q1.y + wz.y * q1.z + ((i == j4 + 1) ? q1.w : 0.f);
            v.z = wr.z * q2.x + wn.z * q2.y + wz.z * q2.z + ((i == j4 + 2) ? q2.w : 0.f);
            v.w = wr.w * q3.x + wn.w * q3.y + wz.w * q3.z + ((i == j4 + 3) ? q3.w : 0.f);
            *(float4*)(ob + i * 128 + j4) = v;
        }
    }
}

// ---------------- K4: y = h_last @ W_y^T + b_y ----------------
__global__ void k4_y(const float* __restrict__ hlast, const float* __restrict__ wy,
                     const float* __restrict__ by, float* __restrict__ out) {
    int t = threadIdx.x;          // 1024
    int b = t >> 5, o = t & 31;
    const float* hr = hlast + b * 128;
    const float* wr = wy + o * 128;
    float acc = 0.f;
    #pragma unroll 4
    for (int k = 0; k < 128; k++) acc += hr[k] * wr[k];
    out[t] = acc + by[o];
}

extern "C" void kernel_launch(void* const* d_in, const int* in_sizes, int n_in,
                              void* d_out, int out_size, void* d_ws, size_t ws_size,
                              hipStream_t stream) {
    const float* x   = (const float*)d_in[0];
    const float* Wih = (const float*)d_in[1];
    const float* Whh = (const float*)d_in[2];
    const float* bih = (const float*)d_in[3];
    const float* bhh = (const float*)d_in[4];
    const float* Wy  = (const float*)d_in[5];
    const float* by  = (const float*)d_in[6];
    float* out = (float*)d_out;
    float* ws  = (float*)d_ws;

    float*  ih    = ws;                              // 6,291,456 floats
    float4* coef  = (float4*)(ws + 6291456);         // 8,388,608 floats
    float*  wt    = ws + 6291456 + 8388608;          // 49,152 floats
    float*  hlast = wt + 49152;                      // 4,096 floats

    k0_transpose<<<192, 256, 0, stream>>>(Whh, wt);
    k1_gemm_ih<<<dim3(256, 6), 256, 0, stream>>>(x, Wih, bih, ih);
    k2_scan<<<32, 384, 0, stream>>>(ih, Whh, bhh, coef, hlast);
    k3_jac<<<dim3(256, 4), 256, 0, stream>>>(coef, wt, out);
    k4_y<<<1, 1024, 0, stream>>>(hlast, Wy, by, out);
}